// Round 6
// baseline (537.622 us; speedup 1.0000x reference)
//
#include <hip/hip_runtime.h>

// CRF forward: B=512 chains, T=1024, L=48.
// One launch of 1024 blocks:
//   blocks 0..511   : serial alpha-scan, one wave per chain (reads y_pred only)
//   blocks 512..1023: point+trans scores, fully parallel (reads y_true/y_pred)
// Combined into out[b] via two atomicAdds (bitwise-deterministic: 2 adds
// commute) after hipMemsetAsync(out, 0).
// Scan step: ds_write + 12 uniform ds_read_b128 (HW broadcast) + 48 VGPR fmacs.
// Normalizer: DAMPED lag-2. c_t = 0.5*log2(e_{t-2}[0]) -> recurrence
// a_t = a_{t-1} + g_t - 0.5*a_{t-2} has poles (1±i)/2, |z|=0.707: stable
// (raw lag-2 had poles ON the unit circle -> random-walk overflow -> R4 NaN).
// Exactness is independent of c (S accumulates exactly what w subtracts).

constexpr int Bb = 512;
constexpr int Tt = 1024;
constexpr int Ll = 48;
constexpr int PF = 4;   // prefetch depth (steps)

#define LOG2E_F 1.44269504088896340736f
#define LN2_F   0.69314718055994530942f

__device__ __forceinline__ float rl_f(float v, int l) {
    return __uint_as_float(__builtin_amdgcn_readlane(__float_as_uint(v), (unsigned)l));
}
__device__ __forceinline__ float fexp2(float x) {
    return __builtin_amdgcn_exp2f(x);
}
__device__ __forceinline__ float flog2(float x) {
    return __builtin_amdgcn_logf(x);   // v_log_f32 = log2
}

__global__ __launch_bounds__(64)
__attribute__((amdgpu_waves_per_eu(1, 1)))
void crf_fwd_kernel(const float* __restrict__ y_true,
                    const float* __restrict__ y_pred,
                    const float* __restrict__ trans,
                    float* __restrict__ out)
{
    const int lane = threadIdx.x;
    const int ml   = lane < Ll ? lane : (Ll - 1);
    const bool act = lane < Ll;

    __shared__ float str[Ll * Ll];
    __shared__ __align__(16) float ebuf[64];

    if (blockIdx.x >= Bb) {
        // ---------------- score block: chain b = blockIdx.x - Bb ----------
        const int b = blockIdx.x - Bb;
        for (int i = lane; i < Ll * Ll; i += 64) str[i] = trans[i];
        __syncthreads();

        const float* __restrict__ yprow = y_pred + (size_t)b * Tt * Ll;
        const float* __restrict__ ytrow = y_true + (size_t)b * Tt * Ll;

        float ps = 0.f, ts = 0.f;
        unsigned long long m0 = __ballot(act && (ytrow[ml] > 0.5f));
        int labPrev = __ffsll(m0) - 1;
        if (lane == labPrev) ps += yprow[ml];        // t=0 point term

        for (int t = 1; t < Tt; ++t) {
            float ytv = ytrow[t * Ll + ml];
            unsigned long long bm = __ballot(act && (ytv > 0.5f));
            int lab = __ffsll(bm) - 1;
            if (lane == lab) ps += yprow[t * Ll + ml];   // one active lane
            ts += str[labPrev * Ll + lab];               // uniform broadcast read
            labPrev = lab;
        }
        #pragma unroll
        for (int off = 32; off >= 1; off >>= 1) ps += __shfl_xor(ps, off);
        if (lane == 0) atomicAdd(&out[b], -(ps + ts));
        return;
    }

    // ---------------- scan block: chain b = blockIdx.x --------------------
    const int b = blockIdx.x;
    for (int i = lane; i < Ll * Ll; i += 64) str[i] = trans[i];
    __syncthreads();

    // Et[l] = exp(trans[l][ml]) as 48 named scalars (static accesses only)
#define MK_E(l) float E##l = fexp2(str[(l) * Ll + ml] * LOG2E_F);
    MK_E(0)  MK_E(1)  MK_E(2)  MK_E(3)  MK_E(4)  MK_E(5)  MK_E(6)  MK_E(7)
    MK_E(8)  MK_E(9)  MK_E(10) MK_E(11) MK_E(12) MK_E(13) MK_E(14) MK_E(15)
    MK_E(16) MK_E(17) MK_E(18) MK_E(19) MK_E(20) MK_E(21) MK_E(22) MK_E(23)
    MK_E(24) MK_E(25) MK_E(26) MK_E(27) MK_E(28) MK_E(29) MK_E(30) MK_E(31)
    MK_E(32) MK_E(33) MK_E(34) MK_E(35) MK_E(36) MK_E(37) MK_E(38) MK_E(39)
    MK_E(40) MK_E(41) MK_E(42) MK_E(43) MK_E(44) MK_E(45) MK_E(46) MK_E(47)
#undef MK_E

    const float* __restrict__ yprow = y_pred + (size_t)b * Tt * Ll;

    float raw0 = yprow[ml];
    float e = fexp2(raw0 * LOG2E_F);                  // e_0[m], S = 0
    float S = 0.f;
    float cUse = 0.5f * rl_f(raw0, 0) * LOG2E_F;      // 0.5*log2(e_0[0])

    // Step t: w uses cUse (derived from e_{t-2}); cNew computed from e_{t-1}
    // here, consumed next step -> readlane/log chain overlaps the DS wait.
#define STEP(raw)                                                        \
    do {                                                                 \
        ebuf[lane] = e;                                                  \
        float cNew = 0.5f * flog2(rl_f(e, 0));                           \
        cNew = fminf(50.f, fmaxf(-50.f, cNew));                          \
        float w = fexp2(fmaf((raw), LOG2E_F, -cUse));                    \
        S += cUse;                                                       \
        cUse = cNew;                                                     \
        float a0 = 0.f, a1 = 0.f, a2 = 0.f, a3 = 0.f;                    \
        { float4 bc = *(const float4*)&ebuf[0];                          \
          a0 = fmaf(bc.x, E0,  a0); a1 = fmaf(bc.y, E1,  a1);            \
          a2 = fmaf(bc.z, E2,  a2); a3 = fmaf(bc.w, E3,  a3); }          \
        { float4 bc = *(const float4*)&ebuf[4];                          \
          a0 = fmaf(bc.x, E4,  a0); a1 = fmaf(bc.y, E5,  a1);            \
          a2 = fmaf(bc.z, E6,  a2); a3 = fmaf(bc.w, E7,  a3); }          \
        { float4 bc = *(const float4*)&ebuf[8];                          \
          a0 = fmaf(bc.x, E8,  a0); a1 = fmaf(bc.y, E9,  a1);            \
          a2 = fmaf(bc.z, E10, a2); a3 = fmaf(bc.w, E11, a3); }          \
        { float4 bc = *(const float4*)&ebuf[12];                         \
          a0 = fmaf(bc.x, E12, a0); a1 = fmaf(bc.y, E13, a1);            \
          a2 = fmaf(bc.z, E14, a2); a3 = fmaf(bc.w, E15, a3); }          \
        { float4 bc = *(const float4*)&ebuf[16];                         \
          a0 = fmaf(bc.x, E16, a0); a1 = fmaf(bc.y, E17, a1);            \
          a2 = fmaf(bc.z, E18, a2); a3 = fmaf(bc.w, E19, a3); }          \
        { float4 bc = *(const float4*)&ebuf[20];                         \
          a0 = fmaf(bc.x, E20, a0); a1 = fmaf(bc.y, E21, a1);            \
          a2 = fmaf(bc.z, E22, a2); a3 = fmaf(bc.w, E23, a3); }          \
        { float4 bc = *(const float4*)&ebuf[24];                         \
          a0 = fmaf(bc.x, E24, a0); a1 = fmaf(bc.y, E25, a1);            \
          a2 = fmaf(bc.z, E26, a2); a3 = fmaf(bc.w, E27, a3); }          \
        { float4 bc = *(const float4*)&ebuf[28];                         \
          a0 = fmaf(bc.x, E28, a0); a1 = fmaf(bc.y, E29, a1);            \
          a2 = fmaf(bc.z, E30, a2); a3 = fmaf(bc.w, E31, a3); }          \
        { float4 bc = *(const float4*)&ebuf[32];                         \
          a0 = fmaf(bc.x, E32, a0); a1 = fmaf(bc.y, E33, a1);            \
          a2 = fmaf(bc.z, E34, a2); a3 = fmaf(bc.w, E35, a3); }          \
        { float4 bc = *(const float4*)&ebuf[36];                         \
          a0 = fmaf(bc.x, E36, a0); a1 = fmaf(bc.y, E37, a1);            \
          a2 = fmaf(bc.z, E38, a2); a3 = fmaf(bc.w, E39, a3); }          \
        { float4 bc = *(const float4*)&ebuf[40];                         \
          a0 = fmaf(bc.x, E40, a0); a1 = fmaf(bc.y, E41, a1);            \
          a2 = fmaf(bc.z, E42, a2); a3 = fmaf(bc.w, E43, a3); }          \
        { float4 bc = *(const float4*)&ebuf[44];                         \
          a0 = fmaf(bc.x, E44, a0); a1 = fmaf(bc.y, E45, a1);            \
          a2 = fmaf(bc.z, E46, a2); a3 = fmaf(bc.w, E47, a3); }          \
        e = ((a0 + a1) + (a2 + a3)) * w;                                 \
    } while (0)

    float pfP[PF];
    #pragma unroll
    for (int j = 0; j < PF; ++j) pfP[j] = yprow[(1 + j) * Ll + ml];

    for (int t0 = 1; t0 <= Tt - PF - 3; t0 += PF) {
        #pragma unroll
        for (int j = 0; j < PF; ++j) {
            float raw = pfP[j];
            int tn = t0 + j + PF;
            tn = tn < Tt ? tn : (Tt - 1);       // clamp (harmless reload)
            pfP[j] = yprow[tn * Ll + ml];
            STEP(raw);
        }
    }
    STEP(pfP[0]);
    STEP(pfP[1]);
    STEP(pfP[2]);
#undef STEP

    float es = act ? e : 0.f;
    #pragma unroll
    for (int off = 32; off >= 1; off >>= 1) es += __shfl_xor(es, off);

    if (lane == 0)
        atomicAdd(&out[b], LN2_F * (S + flog2(es)));
}

extern "C" void kernel_launch(void* const* d_in, const int* in_sizes, int n_in,
                              void* d_out, int out_size, void* d_ws, size_t ws_size,
                              hipStream_t stream) {
    const float* y_true = (const float*)d_in[0];
    const float* y_pred = (const float*)d_in[1];
    const float* trans  = (const float*)d_in[2];
    float* out = (float*)d_out;

    hipMemsetAsync(d_out, 0, (size_t)out_size * sizeof(float), stream);
    crf_fwd_kernel<<<2 * Bb, 64, 0, stream>>>(y_true, y_pred, trans, out);
}

// Round 7
// 257.211 us; speedup vs baseline: 2.0902x; 2.0902x over previous
//
#include <hip/hip_runtime.h>

// CRF forward: B=512 chains, T=1024, L=48.
// One launch of 1024 blocks:
//   blocks 0..511   : serial alpha-scan, one wave per chain (reads y_pred only)
//   blocks 512..1023: point+trans scores, PARALLEL over t (lane j <-> t0+j)
// Combined into out[b] via two atomicAdds (bitwise-deterministic: 2 adds
// commute) after hipMemsetAsync(out, 0).
// Scan step: ds_write + 12 uniform ds_read_b128 (HW broadcast) + 48 VGPR fmacs.
// Normalizer: damped lag-2 (c_t = 0.5*log2(e_{t-2}[0]), poles |z|=0.707,
// stable; validated R5 absmax=0). Exactness independent of c.

constexpr int Bb = 512;
constexpr int Tt = 1024;
constexpr int Ll = 48;
constexpr int PF = 4;   // scan prefetch depth (steps)

#define LOG2E_F 1.44269504088896340736f
#define LN2_F   0.69314718055994530942f

__device__ __forceinline__ float rl_f(float v, int l) {
    return __uint_as_float(__builtin_amdgcn_readlane(__float_as_uint(v), (unsigned)l));
}
__device__ __forceinline__ float fexp2(float x) {
    return __builtin_amdgcn_exp2f(x);
}
__device__ __forceinline__ float flog2(float x) {
    return __builtin_amdgcn_logf(x);   // v_log_f32 = log2
}

__global__ __launch_bounds__(64)
__attribute__((amdgpu_waves_per_eu(1, 1)))
void crf_fwd_kernel(const float* __restrict__ y_true,
                    const float* __restrict__ y_pred,
                    const float* __restrict__ trans,
                    float* __restrict__ out)
{
    const int lane = threadIdx.x;

    __shared__ float str[Ll * Ll];
    __shared__ __align__(16) float ebuf[64];

    if (blockIdx.x >= Bb) {
        // -------- score block: chain b, parallel over t (lane j = t0+j) ----
        const int b = blockIdx.x - Bb;
        for (int i = lane; i < Ll * Ll; i += 64) str[i] = trans[i];
        __syncthreads();

        const float* __restrict__ yprow = y_pred + (size_t)b * Tt * Ll;
        const float* __restrict__ ytrow = y_true + (size_t)b * Tt * Ll;

        float ps = 0.f, ts = 0.f;
        int labLast = 0;                         // lab at t0-1 (unused for t=0)

        for (int t0 = 0; t0 < Tt; t0 += 64) {
            const int t = t0 + lane;
            // label of row t: 12 independent float4 loads + predicated selects
            const float4* row = (const float4*)(ytrow + (size_t)t * Ll);
            int lab = 0;
            #pragma unroll
            for (int k = 0; k < 12; ++k) {
                float4 v = row[k];
                if (v.x > 0.5f) lab = 4 * k + 0;
                if (v.y > 0.5f) lab = 4 * k + 1;
                if (v.z > 0.5f) lab = 4 * k + 2;
                if (v.w > 0.5f) lab = 4 * k + 3;
            }
            ps += yprow[(size_t)t * Ll + lab];            // point term
            int labPrev = __shfl_up(lab, 1);
            if (lane == 0) labPrev = labLast;             // chunk boundary
            if (t > 0) ts += str[labPrev * Ll + lab];     // trans term
            labLast = __builtin_amdgcn_readlane(lab, 63);
        }

        float acc = ps + ts;
        #pragma unroll
        for (int off = 32; off >= 1; off >>= 1) acc += __shfl_xor(acc, off);
        if (lane == 0) atomicAdd(&out[b], -acc);
        return;
    }

    // ---------------- scan block: chain b = blockIdx.x --------------------
    const int b  = blockIdx.x;
    const int ml = lane < Ll ? lane : (Ll - 1);
    const bool act = lane < Ll;
    for (int i = lane; i < Ll * Ll; i += 64) str[i] = trans[i];
    __syncthreads();

    // Et[l] = exp(trans[l][ml]) as 48 named scalars (static accesses only)
#define MK_E(l) float E##l = fexp2(str[(l) * Ll + ml] * LOG2E_F);
    MK_E(0)  MK_E(1)  MK_E(2)  MK_E(3)  MK_E(4)  MK_E(5)  MK_E(6)  MK_E(7)
    MK_E(8)  MK_E(9)  MK_E(10) MK_E(11) MK_E(12) MK_E(13) MK_E(14) MK_E(15)
    MK_E(16) MK_E(17) MK_E(18) MK_E(19) MK_E(20) MK_E(21) MK_E(22) MK_E(23)
    MK_E(24) MK_E(25) MK_E(26) MK_E(27) MK_E(28) MK_E(29) MK_E(30) MK_E(31)
    MK_E(32) MK_E(33) MK_E(34) MK_E(35) MK_E(36) MK_E(37) MK_E(38) MK_E(39)
    MK_E(40) MK_E(41) MK_E(42) MK_E(43) MK_E(44) MK_E(45) MK_E(46) MK_E(47)
#undef MK_E

    const float* __restrict__ yprow = y_pred + (size_t)b * Tt * Ll;

    float raw0 = yprow[ml];
    float e = fexp2(raw0 * LOG2E_F);                  // e_0[m], S = 0
    float S = 0.f;
    float cUse = 0.5f * rl_f(raw0, 0) * LOG2E_F;      // 0.5*log2(e_0[0])

#define STEP(raw)                                                        \
    do {                                                                 \
        ebuf[lane] = e;                                                  \
        float cNew = 0.5f * flog2(rl_f(e, 0));                           \
        cNew = fminf(50.f, fmaxf(-50.f, cNew));                          \
        float w = fexp2(fmaf((raw), LOG2E_F, -cUse));                    \
        S += cUse;                                                       \
        cUse = cNew;                                                     \
        float a0 = 0.f, a1 = 0.f, a2 = 0.f, a3 = 0.f;                    \
        { float4 bc = *(const float4*)&ebuf[0];                          \
          a0 = fmaf(bc.x, E0,  a0); a1 = fmaf(bc.y, E1,  a1);            \
          a2 = fmaf(bc.z, E2,  a2); a3 = fmaf(bc.w, E3,  a3); }          \
        { float4 bc = *(const float4*)&ebuf[4];                          \
          a0 = fmaf(bc.x, E4,  a0); a1 = fmaf(bc.y, E5,  a1);            \
          a2 = fmaf(bc.z, E6,  a2); a3 = fmaf(bc.w, E7,  a3); }          \
        { float4 bc = *(const float4*)&ebuf[8];                          \
          a0 = fmaf(bc.x, E8,  a0); a1 = fmaf(bc.y, E9,  a1);            \
          a2 = fmaf(bc.z, E10, a2); a3 = fmaf(bc.w, E11, a3); }          \
        { float4 bc = *(const float4*)&ebuf[12];                         \
          a0 = fmaf(bc.x, E12, a0); a1 = fmaf(bc.y, E13, a1);            \
          a2 = fmaf(bc.z, E14, a2); a3 = fmaf(bc.w, E15, a3); }          \
        { float4 bc = *(const float4*)&ebuf[16];                         \
          a0 = fmaf(bc.x, E16, a0); a1 = fmaf(bc.y, E17, a1);            \
          a2 = fmaf(bc.z, E18, a2); a3 = fmaf(bc.w, E19, a3); }          \
        { float4 bc = *(const float4*)&ebuf[20];                         \
          a0 = fmaf(bc.x, E20, a0); a1 = fmaf(bc.y, E21, a1);            \
          a2 = fmaf(bc.z, E22, a2); a3 = fmaf(bc.w, E23, a3); }          \
        { float4 bc = *(const float4*)&ebuf[24];                         \
          a0 = fmaf(bc.x, E24, a0); a1 = fmaf(bc.y, E25, a1);            \
          a2 = fmaf(bc.z, E26, a2); a3 = fmaf(bc.w, E27, a3); }          \
        { float4 bc = *(const float4*)&ebuf[28];                         \
          a0 = fmaf(bc.x, E28, a0); a1 = fmaf(bc.y, E29, a1);            \
          a2 = fmaf(bc.z, E30, a2); a3 = fmaf(bc.w, E31, a3); }          \
        { float4 bc = *(const float4*)&ebuf[32];                         \
          a0 = fmaf(bc.x, E32, a0); a1 = fmaf(bc.y, E33, a1);            \
          a2 = fmaf(bc.z, E34, a2); a3 = fmaf(bc.w, E35, a3); }          \
        { float4 bc = *(const float4*)&ebuf[36];                         \
          a0 = fmaf(bc.x, E36, a0); a1 = fmaf(bc.y, E37, a1);            \
          a2 = fmaf(bc.z, E38, a2); a3 = fmaf(bc.w, E39, a3); }          \
        { float4 bc = *(const float4*)&ebuf[40];                         \
          a0 = fmaf(bc.x, E40, a0); a1 = fmaf(bc.y, E41, a1);            \
          a2 = fmaf(bc.z, E42, a2); a3 = fmaf(bc.w, E43, a3); }          \
        { float4 bc = *(const float4*)&ebuf[44];                         \
          a0 = fmaf(bc.x, E44, a0); a1 = fmaf(bc.y, E45, a1);            \
          a2 = fmaf(bc.z, E46, a2); a3 = fmaf(bc.w, E47, a3); }          \
        e = ((a0 + a1) + (a2 + a3)) * w;                                 \
    } while (0)

    float pfP[PF];
    #pragma unroll
    for (int j = 0; j < PF; ++j) pfP[j] = yprow[(1 + j) * Ll + ml];

    for (int t0 = 1; t0 <= Tt - PF - 3; t0 += PF) {
        #pragma unroll
        for (int j = 0; j < PF; ++j) {
            float raw = pfP[j];
            int tn = t0 + j + PF;
            tn = tn < Tt ? tn : (Tt - 1);       // clamp (harmless reload)
            pfP[j] = yprow[tn * Ll + ml];
            STEP(raw);
        }
    }
    STEP(pfP[0]);
    STEP(pfP[1]);
    STEP(pfP[2]);
#undef STEP

    float es = act ? e : 0.f;
    #pragma unroll
    for (int off = 32; off >= 1; off >>= 1) es += __shfl_xor(es, off);

    if (lane == 0)
        atomicAdd(&out[b], LN2_F * (S + flog2(es)));
}

extern "C" void kernel_launch(void* const* d_in, const int* in_sizes, int n_in,
                              void* d_out, int out_size, void* d_ws, size_t ws_size,
                              hipStream_t stream) {
    const float* y_true = (const float*)d_in[0];
    const float* y_pred = (const float*)d_in[1];
    const float* trans  = (const float*)d_in[2];
    float* out = (float*)d_out;

    hipMemsetAsync(d_out, 0, (size_t)out_size * sizeof(float), stream);
    crf_fwd_kernel<<<2 * Bb, 64, 0, stream>>>(y_true, y_pred, trans, out);
}

// Round 8
// 182.795 us; speedup vs baseline: 2.9411x; 1.4071x over previous
//
#include <hip/hip_runtime.h>

// CRF forward: B=512 chains, T=1024, L=48.
// One launch of 1024 blocks:
//   blocks 0..511   : serial alpha-scan, one wave per chain (reads y_pred only)
//   blocks 512..1023: point+trans scores, PARALLEL over t (lane j <-> t0+j)
// Combined into out[b] via two atomicAdds after hipMemsetAsync(out, 0).
//
// Scan step (R7): PURE-VALU broadcast. e'[m] = (sum_l readlane(e,l)*Et[l][m])*w.
// 48 v_readlane + 48 v_fmac (SGPR operand), no DS pipe, no waitcnt on the
// critical path (R0-R6 showed the LDS write->read round trip costs ~590cy/step;
// R0's readlane attempt was poisoned by scratch-spilled Et - VGPR_Count=48).
// 8 accumulators -> dependent-fmac depth 6.
// Normalizer: damped lag-2 (c_t = 0.5*log2(e_{t-2}[0]), poles |z|=0.707,
// stable; validated R5/R6 absmax=0). Exactness independent of c.

constexpr int Bb = 512;
constexpr int Tt = 1024;
constexpr int Ll = 48;
constexpr int PF = 4;   // scan prefetch depth (steps)

#define LOG2E_F 1.44269504088896340736f
#define LN2_F   0.69314718055994530942f

__device__ __forceinline__ float rl_f(float v, int l) {
    return __uint_as_float(__builtin_amdgcn_readlane(__float_as_uint(v), (unsigned)l));
}
__device__ __forceinline__ float fexp2(float x) {
    return __builtin_amdgcn_exp2f(x);
}
__device__ __forceinline__ float flog2(float x) {
    return __builtin_amdgcn_logf(x);   // v_log_f32 = log2
}

__global__ __launch_bounds__(64)
__attribute__((amdgpu_waves_per_eu(1, 1)))
void crf_fwd_kernel(const float* __restrict__ y_true,
                    const float* __restrict__ y_pred,
                    const float* __restrict__ trans,
                    float* __restrict__ out)
{
    const int lane = threadIdx.x;

    __shared__ float str[Ll * Ll];

    if (blockIdx.x >= Bb) {
        // -------- score block: chain b, parallel over t (lane j = t0+j) ----
        const int b = blockIdx.x - Bb;
        for (int i = lane; i < Ll * Ll; i += 64) str[i] = trans[i];
        __syncthreads();

        const float* __restrict__ yprow = y_pred + (size_t)b * Tt * Ll;
        const float* __restrict__ ytrow = y_true + (size_t)b * Tt * Ll;

        float ps = 0.f, ts = 0.f;
        int labLast = 0;                         // lab at t0-1 (unused for t=0)

        for (int t0 = 0; t0 < Tt; t0 += 64) {
            const int t = t0 + lane;
            // label of row t: 12 independent float4 loads + predicated selects
            const float4* row = (const float4*)(ytrow + (size_t)t * Ll);
            int lab = 0;
            #pragma unroll
            for (int k = 0; k < 12; ++k) {
                float4 v = row[k];
                if (v.x > 0.5f) lab = 4 * k + 0;
                if (v.y > 0.5f) lab = 4 * k + 1;
                if (v.z > 0.5f) lab = 4 * k + 2;
                if (v.w > 0.5f) lab = 4 * k + 3;
            }
            ps += yprow[(size_t)t * Ll + lab];            // point term
            int labPrev = __shfl_up(lab, 1);
            if (lane == 0) labPrev = labLast;             // chunk boundary
            if (t > 0) ts += str[labPrev * Ll + lab];     // trans term
            labLast = __builtin_amdgcn_readlane(lab, 63);
        }

        float acc = ps + ts;
        #pragma unroll
        for (int off = 32; off >= 1; off >>= 1) acc += __shfl_xor(acc, off);
        if (lane == 0) atomicAdd(&out[b], -acc);
        return;
    }

    // ---------------- scan block: chain b = blockIdx.x --------------------
    const int b  = blockIdx.x;
    const int ml = lane < Ll ? lane : (Ll - 1);
    const bool act = lane < Ll;
    for (int i = lane; i < Ll * Ll; i += 64) str[i] = trans[i];
    __syncthreads();

    // Et[l] = exp(trans[l][ml]) as 48 named scalars (static accesses only)
#define MK_E(l) float E##l = fexp2(str[(l) * Ll + ml] * LOG2E_F);
    MK_E(0)  MK_E(1)  MK_E(2)  MK_E(3)  MK_E(4)  MK_E(5)  MK_E(6)  MK_E(7)
    MK_E(8)  MK_E(9)  MK_E(10) MK_E(11) MK_E(12) MK_E(13) MK_E(14) MK_E(15)
    MK_E(16) MK_E(17) MK_E(18) MK_E(19) MK_E(20) MK_E(21) MK_E(22) MK_E(23)
    MK_E(24) MK_E(25) MK_E(26) MK_E(27) MK_E(28) MK_E(29) MK_E(30) MK_E(31)
    MK_E(32) MK_E(33) MK_E(34) MK_E(35) MK_E(36) MK_E(37) MK_E(38) MK_E(39)
    MK_E(40) MK_E(41) MK_E(42) MK_E(43) MK_E(44) MK_E(45) MK_E(46) MK_E(47)
#undef MK_E

    const float* __restrict__ yprow = y_pred + (size_t)b * Tt * Ll;

    float raw0 = yprow[ml];
    float e = fexp2(raw0 * LOG2E_F);                  // e_0[m], S = 0
    float S = 0.f;
    float cUse = 0.5f * rl_f(raw0, 0) * LOG2E_F;      // 0.5*log2(e_0[0])

    // one fmac of the broadcast matvec: acc += readlane(e,l) * Et[l][m]
#define RLF(l, acc) acc = fmaf(rl_f(e, l), E##l, acc);

#define STEP(raw)                                                        \
    do {                                                                 \
        float cNew = 0.5f * flog2(rl_f(e, 0));                           \
        cNew = fminf(50.f, fmaxf(-50.f, cNew));                          \
        float w = fexp2(fmaf((raw), LOG2E_F, -cUse));                    \
        S += cUse;                                                       \
        cUse = cNew;                                                     \
        float a0 = 0.f, a1 = 0.f, a2 = 0.f, a3 = 0.f;                    \
        float a4 = 0.f, a5 = 0.f, a6 = 0.f, a7 = 0.f;                    \
        RLF(0,  a0) RLF(1,  a1) RLF(2,  a2) RLF(3,  a3)                  \
        RLF(4,  a4) RLF(5,  a5) RLF(6,  a6) RLF(7,  a7)                  \
        RLF(8,  a0) RLF(9,  a1) RLF(10, a2) RLF(11, a3)                  \
        RLF(12, a4) RLF(13, a5) RLF(14, a6) RLF(15, a7)                  \
        RLF(16, a0) RLF(17, a1) RLF(18, a2) RLF(19, a3)                  \
        RLF(20, a4) RLF(21, a5) RLF(22, a6) RLF(23, a7)                  \
        RLF(24, a0) RLF(25, a1) RLF(26, a2) RLF(27, a3)                  \
        RLF(28, a4) RLF(29, a5) RLF(30, a6) RLF(31, a7)                  \
        RLF(32, a0) RLF(33, a1) RLF(34, a2) RLF(35, a3)                  \
        RLF(36, a4) RLF(37, a5) RLF(38, a6) RLF(39, a7)                  \
        RLF(40, a0) RLF(41, a1) RLF(42, a2) RLF(43, a3)                  \
        RLF(44, a4) RLF(45, a5) RLF(46, a6) RLF(47, a7)                  \
        e = (((a0 + a1) + (a2 + a3)) + ((a4 + a5) + (a6 + a7))) * w;     \
    } while (0)

    float pfP[PF];
    #pragma unroll
    for (int j = 0; j < PF; ++j) pfP[j] = yprow[(1 + j) * Ll + ml];

    for (int t0 = 1; t0 <= Tt - PF - 3; t0 += PF) {
        #pragma unroll
        for (int j = 0; j < PF; ++j) {
            float raw = pfP[j];
            int tn = t0 + j + PF;
            tn = tn < Tt ? tn : (Tt - 1);       // clamp (harmless reload)
            pfP[j] = yprow[tn * Ll + ml];
            STEP(raw);
        }
    }
    STEP(pfP[0]);
    STEP(pfP[1]);
    STEP(pfP[2]);
#undef STEP
#undef RLF

    float es = act ? e : 0.f;
    #pragma unroll
    for (int off = 32; off >= 1; off >>= 1) es += __shfl_xor(es, off);

    if (lane == 0)
        atomicAdd(&out[b], LN2_F * (S + flog2(es)));
}

extern "C" void kernel_launch(void* const* d_in, const int* in_sizes, int n_in,
                              void* d_out, int out_size, void* d_ws, size_t ws_size,
                              hipStream_t stream) {
    const float* y_true = (const float*)d_in[0];
    const float* y_pred = (const float*)d_in[1];
    const float* trans  = (const float*)d_in[2];
    float* out = (float*)d_out;

    hipMemsetAsync(d_out, 0, (size_t)out_size * sizeof(float), stream);
    crf_fwd_kernel<<<2 * Bb, 64, 0, stream>>>(y_true, y_pred, trans, out);
}